// Round 6
// baseline (254.584 us; speedup 1.0000x reference)
//
#include <hip/hip_runtime.h>
#include <math.h>

#define N_MARGIN 0.3f
// Gram: 256x256 C-tile, 8 waves (2Mx4N, each 128x64 = 8x4 frags of 16x16x32
// bf16), BK=32, 4-slot LDS ring staged 3 K-tiles ahead, counted vmcnt(12)
// (never 0 in main loop). Upper-tri supergrid (136 = 8*17 tiles), XCD-chunked.
#define BM 256
#define BK 32

typedef __attribute__((ext_vector_type(8))) short bf16x8;
typedef __attribute__((ext_vector_type(4))) float f32x4;
typedef __attribute__((address_space(3))) unsigned int lds_uint;
typedef __attribute__((address_space(1))) unsigned int gbl_uint;

#define WAITV(N) asm volatile("s_waitcnt vmcnt(" #N ")" ::: "memory")
static __device__ __forceinline__ void wgbar() {
    asm volatile("" ::: "memory");
    __builtin_amdgcn_s_barrier();
    asm volatile("" ::: "memory");
}

// float -> bf16 RNE
static __device__ inline unsigned short f2bf(float f) {
    unsigned int u = __builtin_bit_cast(unsigned int, f);
    u = (u + 0x7fffu + ((u >> 16) & 1u)) >> 16;
    return (unsigned short)u;
}

// ---------------------------------------------------------------------------
// Kernel 1: per-row L2-normalize + bf16 convert, one pass (row in registers).
// ---------------------------------------------------------------------------
__global__ __launch_bounds__(256)
void norm_cvt_k(const float* __restrict__ X, unsigned short* __restrict__ Xb,
                float* __restrict__ rowsq, int d) {
    const int lane = threadIdx.x & 63;
    const int row = blockIdx.x * 4 + (threadIdx.x >> 6);
    const float* xr = X + (size_t)row * d;

    float4 v[8];
    float ss = 0.f;
#pragma unroll
    for (int c = 0; c < 8; ++c) {
        v[c] = *reinterpret_cast<const float4*>(xr + lane * 4 + c * 256);
        ss += v[c].x * v[c].x + v[c].y * v[c].y + v[c].z * v[c].z + v[c].w * v[c].w;
    }
#pragma unroll
    for (int m = 32; m > 0; m >>= 1) ss += __shfl_xor(ss, m);
    float nrm = sqrtf(ss);
    float inv = 1.f / (nrm + 1e-12f);
    if (lane == 0) {
        float s = nrm * inv;
        rowsq[row] = s * s;
    }
    unsigned short* xb = Xb + (size_t)row * d;
#pragma unroll
    for (int c = 0; c < 8; ++c) {
        uint2 o;
        o.x = (unsigned)f2bf(v[c].x * inv) | ((unsigned)f2bf(v[c].y * inv) << 16);
        o.y = (unsigned)f2bf(v[c].z * inv) | ((unsigned)f2bf(v[c].w * inv) << 16);
        *reinterpret_cast<uint2*>(xb + lane * 4 + c * 256) = o;
    }
}

// ---------------------------------------------------------------------------
// Kernel 2: 256^2 bf16 MFMA Gram (upper-tri supertiles) + fused stats.
// 4-slot LDS ring, staged 3 ahead, counted vmcnt; swizzle phys = g^((row>>1)&3)
// (2 lanes/bank = free); linear gload_lds dest + inverse-swizzled source.
// Per K-tile: [stage(t+3); vmcnt(12); bar; ds_read + 32 MFMA; bar].
// ---------------------------------------------------------------------------
__global__ __launch_bounds__(512, 2)
void gram_stats_k(const unsigned short* __restrict__ Xb, const int* __restrict__ tgt,
                  const float* __restrict__ rowsq, float* __restrict__ stats,
                  int n, int d, int nblocks) {
    __shared__ alignas(16) unsigned short As[4][BM * BK];   // 4 x 16KB
    __shared__ alignas(16) unsigned short Bs[4][BM * BK];
    __shared__ int   s_ti[BM], s_tj[BM];
    __shared__ float s_qi[BM], s_qj[BM];

    const int tid = threadIdx.x;
    const int lane = tid & 63;
    const int w = tid >> 6;              // wave 0..7
    const int wr = w >> 2, wc = w & 3;   // 2M x 4N

    const int cpx = nblocks >> 3;        // 136 = 8*17 -> bijective XCD chunk
    const int swz = (blockIdx.x & 7) * cpx + (blockIdx.x >> 3);

    const int nbx = n / BM;              // 16
    int by = 0, rem = swz;
    while (rem >= nbx - by) { rem -= nbx - by; ++by; }
    const int bx = by + rem;
    const bool offdiag = (by != bx);
    const int row0 = by * BM, col0 = bx * BM;

    if (tid < BM) {
        s_ti[tid] = tgt[row0 + tid];
        s_qi[tid] = rowsq[row0 + tid];
    } else {
        int t2 = tid - BM;
        s_tj[t2] = tgt[col0 + t2];
        s_qj[t2] = rowsq[col0 + t2];
    }
    __syncthreads();   // full drain: vmcnt==0 before pipeline ledger starts

    f32x4 acc[8][4];
#pragma unroll
    for (int a = 0; a < 8; ++a)
#pragma unroll
        for (int b = 0; b < 4; ++b) acc[a][b] = (f32x4){0.f, 0.f, 0.f, 0.f};

    // staging: instr grp=2w+q covers rows 16grp..+15; lane l -> row 16grp+(l>>2),
    // phys chunk l&3, global chunk (l&3)^((l>>3)&3)
    const int st_r = lane >> 2;
    const int st_g = (lane & 3) ^ ((lane >> 3) & 3);
    // frag read: phys = (lane>>4) ^ ((lane>>1)&3)
    const int rd_p = (lane >> 4) ^ ((lane >> 1) & 3);

    auto STAGE = [&](int kt) {
        const int s = kt & 3;
        const int k0 = kt * BK;
#pragma unroll
        for (int q = 0; q < 2; ++q) {
            int grp = 2 * w + q;
            const unsigned short* ga =
                Xb + (size_t)(row0 + 16 * grp + st_r) * d + k0 + st_g * 8;
            __builtin_amdgcn_global_load_lds((const gbl_uint*)ga,
                                             (lds_uint*)(&As[s][grp * 512]), 16, 0, 0);
            const unsigned short* gb =
                Xb + (size_t)(col0 + 16 * grp + st_r) * d + k0 + st_g * 8;
            __builtin_amdgcn_global_load_lds((const gbl_uint*)gb,
                                             (lds_uint*)(&Bs[s][grp * 512]), 16, 0, 0);
        }
    };

    auto COMP = [&](int kt) {
        const int s = kt & 3;
        bf16x8 af[8], bf2[4];
#pragma unroll
        for (int fr = 0; fr < 8; ++fr) {
            int rA = wr * 128 + fr * 16 + (lane & 15);
            af[fr] = *reinterpret_cast<const bf16x8*>(&As[s][rA * 32 + rd_p * 8]);
        }
#pragma unroll
        for (int nc = 0; nc < 4; ++nc) {
            int rB = wc * 64 + nc * 16 + (lane & 15);
            bf2[nc] = *reinterpret_cast<const bf16x8*>(&Bs[s][rB * 32 + rd_p * 8]);
        }
        __builtin_amdgcn_s_setprio(1);
#pragma unroll
        for (int fr = 0; fr < 8; ++fr)
#pragma unroll
            for (int nc = 0; nc < 4; ++nc)
                acc[fr][nc] = __builtin_amdgcn_mfma_f32_16x16x32_bf16(
                    af[fr], bf2[nc], acc[fr][nc], 0, 0, 0);
        __builtin_amdgcn_s_setprio(0);
    };

    const int nt = d / BK;               // 64
    STAGE(0); STAGE(1); STAGE(2);        // 12 own-loads in flight

    for (int t = 0; t < nt - 3; ++t) {   // stages tiles 3..nt-1
        STAGE(t + 3);
        WAITV(12);                       // tile t landed (in-flight: t+1..t+3)
        wgbar();
        COMP(t);
        wgbar();
    }
    WAITV(8);  wgbar(); COMP(nt - 3); wgbar();
    WAITV(4);  wgbar(); COMP(nt - 2); wgbar();
    WAITV(0);  wgbar(); COMP(nt - 1); wgbar();

    // Epilogue: row = wr*128 + fr*16 + (lane>>4)*4 + j; col = wc*64 + nc*16 + (lane&15)
    int tjv[4]; float qjv[4];
#pragma unroll
    for (int nc = 0; nc < 4; ++nc) {
        int cloc = wc * 64 + nc * 16 + (lane & 15);
        tjv[nc] = s_tj[cloc];
        qjv[nc] = s_qj[cloc];
    }
    float cs0[4], cs1[4], cs2[4], cs3[4];
#pragma unroll
    for (int nc = 0; nc < 4; ++nc) { cs0[nc] = 0.f; cs1[nc] = 0.f; cs2[nc] = 0.f; cs3[nc] = 0.f; }

#pragma unroll
    for (int fr = 0; fr < 8; ++fr) {
#pragma unroll
        for (int j = 0; j < 4; ++j) {
            int rloc = wr * 128 + fr * 16 + (lane >> 4) * 4 + j;
            int grow = row0 + rloc;
            int ti = s_ti[rloc];
            float sqi = s_qi[rloc];
            float pd = 0.f, pn = 0.f, nd = 0.f, nn = 0.f;
#pragma unroll
            for (int nc = 0; nc < 4; ++nc) {
                int gcol = col0 + wc * 64 + nc * 16 + (lane & 15);
                float g = acc[fr][nc][j];
                float d2 = sqi + qjv[nc] - 2.f * g;
                float dist = sqrtf(fmaxf(d2, 1e-12f));
                if (ti == tjv[nc]) {
                    if (grow != gcol) {
                        float e = __expf(dist);
                        pd += e; pn += e * dist;
                        cs0[nc] += e; cs1[nc] += e * dist;
                    }
                } else {
                    float e = __expf(-dist);
                    nd += e; nn += e * dist;
                    cs2[nc] += e; cs3[nc] += e * dist;
                }
            }
            for (int m = 1; m < 16; m <<= 1) {
                pd += __shfl_xor(pd, m);
                pn += __shfl_xor(pn, m);
                nd += __shfl_xor(nd, m);
                nn += __shfl_xor(nn, m);
            }
            if ((lane & 15) == 0) {
                atomicAdd(&stats[grow * 4 + 0], pd);
                atomicAdd(&stats[grow * 4 + 1], pn);
                atomicAdd(&stats[grow * 4 + 2], nd);
                atomicAdd(&stats[grow * 4 + 3], nn);
            }
        }
    }

    if (offdiag) {
#pragma unroll
        for (int nc = 0; nc < 4; ++nc) {
            float a = cs0[nc], b = cs1[nc], c = cs2[nc], e = cs3[nc];
            for (int m = 16; m < 64; m <<= 1) {
                a += __shfl_xor(a, m);
                b += __shfl_xor(b, m);
                c += __shfl_xor(c, m);
                e += __shfl_xor(e, m);
            }
            if (lane < 16) {
                int gcol = col0 + wc * 64 + nc * 16 + lane;
                atomicAdd(&stats[gcol * 4 + 0], a);
                atomicAdd(&stats[gcol * 4 + 1], b);
                atomicAdd(&stats[gcol * 4 + 2], c);
                atomicAdd(&stats[gcol * 4 + 3], e);
            }
        }
    }
}

// ---------------------------------------------------------------------------
// Kernel 3: finalize — loss = mean(relu(pos + MARGIN - neg))
// ---------------------------------------------------------------------------
__global__ void finalize_k(const float* __restrict__ stats, float* __restrict__ out, int n) {
    float s = 0.f;
    for (int i = threadIdx.x; i < n; i += blockDim.x) {
        float4 st = *reinterpret_cast<const float4*>(&stats[i * 4]);
        float v = st.y / st.x + N_MARGIN - st.w / st.z;
        s += fmaxf(v, 0.f);
    }
    for (int m = 32; m > 0; m >>= 1) s += __shfl_down(s, m);
    __shared__ float sp[4];
    int lane = threadIdx.x & 63, wv = threadIdx.x >> 6;
    if (lane == 0) sp[wv] = s;
    __syncthreads();
    if (threadIdx.x == 0) out[0] = (sp[0] + sp[1] + sp[2] + sp[3]) / (float)n;
}

extern "C" void kernel_launch(void* const* d_in, const int* in_sizes, int n_in,
                              void* d_out, int out_size, void* d_ws, size_t ws_size,
                              hipStream_t stream) {
    const float* X = (const float*)d_in[0];
    const int* tgt = (const int*)d_in[1];
    const int n = in_sizes[1];             // 4096
    const int d = in_sizes[0] / n;         // 2048

    unsigned short* Xb = (unsigned short*)d_ws;          // n*d bf16 (16 MB)
    float* rowsq = (float*)(Xb + (size_t)n * d);         // n floats
    float* stats = rowsq + n;                            // 4n floats

    hipMemsetAsync(stats, 0, (size_t)n * 4 * sizeof(float), stream);
    norm_cvt_k<<<n / 4, 256, 0, stream>>>(X, Xb, rowsq, d);
    const int nbx = n / BM;                              // 16
    const int nblocks = nbx * (nbx + 1) / 2;             // 136 upper-tri supertiles
    gram_stats_k<<<nblocks, 512, 0, stream>>>(Xb, tgt, rowsq, stats, n, d, nblocks);
    finalize_k<<<1, 256, 0, stream>>>(stats, (float*)d_out, n);
}

// Round 7
// 242.832 us; speedup vs baseline: 1.0484x; 1.0484x over previous
//
#include <hip/hip_runtime.h>
#include <math.h>

#define N_MARGIN 0.3f
// Gram: 64x64 C-tile, ONE wave per block (64 threads), BK=32, double-buffered
// LDS, ZERO barriers (single wave owns LDS; ordering via counted vmcnt only).
// Upper-tri grid of 64x64 tiles: 2080 blocks = 8*260 (bijective XCD chunk).
// ~10 blocks/CU resident -> 2-3 independent wave-streams per SIMD hide all
// latency (m114); no lockstep drain possible.
#define BM 64
#define BK 32

typedef __attribute__((ext_vector_type(8))) short bf16x8;
typedef __attribute__((ext_vector_type(4))) float f32x4;
typedef __attribute__((address_space(3))) unsigned int lds_uint;
typedef __attribute__((address_space(1))) unsigned int gbl_uint;

#define WAITV(N) asm volatile("s_waitcnt vmcnt(" #N ")" ::: "memory")

// float -> bf16 RNE
static __device__ inline unsigned short f2bf(float f) {
    unsigned int u = __builtin_bit_cast(unsigned int, f);
    u = (u + 0x7fffu + ((u >> 16) & 1u)) >> 16;
    return (unsigned short)u;
}

// ---------------------------------------------------------------------------
// Kernel 1: per-row L2-normalize + bf16 convert, one pass (row in registers).
// ---------------------------------------------------------------------------
__global__ __launch_bounds__(256)
void norm_cvt_k(const float* __restrict__ X, unsigned short* __restrict__ Xb,
                float* __restrict__ rowsq, int d) {
    const int lane = threadIdx.x & 63;
    const int row = blockIdx.x * 4 + (threadIdx.x >> 6);
    const float* xr = X + (size_t)row * d;

    float4 v[8];
    float ss = 0.f;
#pragma unroll
    for (int c = 0; c < 8; ++c) {
        v[c] = *reinterpret_cast<const float4*>(xr + lane * 4 + c * 256);
        ss += v[c].x * v[c].x + v[c].y * v[c].y + v[c].z * v[c].z + v[c].w * v[c].w;
    }
#pragma unroll
    for (int m = 32; m > 0; m >>= 1) ss += __shfl_xor(ss, m);
    float nrm = sqrtf(ss);
    float inv = 1.f / (nrm + 1e-12f);
    if (lane == 0) {
        float s = nrm * inv;
        rowsq[row] = s * s;
    }
    unsigned short* xb = Xb + (size_t)row * d;
#pragma unroll
    for (int c = 0; c < 8; ++c) {
        uint2 o;
        o.x = (unsigned)f2bf(v[c].x * inv) | ((unsigned)f2bf(v[c].y * inv) << 16);
        o.y = (unsigned)f2bf(v[c].z * inv) | ((unsigned)f2bf(v[c].w * inv) << 16);
        *reinterpret_cast<uint2*>(xb + lane * 4 + c * 256) = o;
    }
}

// ---------------------------------------------------------------------------
// Kernel 2: single-wave 64x64 bf16 MFMA Gram tile (upper-tri) + fused stats.
// Pipeline per tile: STAGE(t+1) [8 gload_lds] -> vmcnt(8) [tile t landed]
// -> 8 ds_read_b128 -> 16 MFMA. No barriers.
// Swizzle: LDS[r][phys p] holds global chunk p ^ ((r>>1)&3); 16B-granular;
// linear gload_lds dest + inverse-swizzled global source (rule #21).
// Frag read phys = (lane>>4) ^ ((lane>>1)&3) -> <=2 lanes/bank (free).
// ---------------------------------------------------------------------------
__global__ __launch_bounds__(64, 2)
void gram_stats_k(const unsigned short* __restrict__ Xb, const int* __restrict__ tgt,
                  const float* __restrict__ rowsq, float* __restrict__ stats,
                  int n, int d, int nblocks) {
    __shared__ alignas(16) unsigned short As[2][BM * BK];   // 2 x 4KB
    __shared__ alignas(16) unsigned short Bs[2][BM * BK];

    const int lane = threadIdx.x;        // 64-thread block == one wave

    // T1: bijective XCD chunking (2080 = 8 * 260)
    const int cpx = nblocks >> 3;
    const int swz = (blockIdx.x & 7) * cpx + (blockIdx.x >> 3);

    const int nbx = n / BM;              // 64
    int by = 0, rem = swz;
    while (rem >= nbx - by) { rem -= nbx - by; ++by; }
    const int bx = by + rem;
    const bool offdiag = (by != bx);
    const int row0 = by * BM, col0 = bx * BM;

    f32x4 acc[4][4];
#pragma unroll
    for (int a = 0; a < 4; ++a)
#pragma unroll
        for (int b = 0; b < 4; ++b) acc[a][b] = (f32x4){0.f, 0.f, 0.f, 0.f};

    // staging: instr i covers rows 16i..16i+15 (1KB); lane l -> row 16i+(l>>2),
    // phys chunk l&3, global chunk (l&3)^((l>>3)&3)
    const int st_r = lane >> 2;
    const int st_g = (lane & 3) ^ ((lane >> 3) & 3);
    // frag read: row rX = fr*16+(lane&15), logical chunk lane>>4,
    // phys = (lane>>4) ^ ((rX>>1)&3) = (lane>>4) ^ ((lane>>1)&3)
    const int rd_p = (lane >> 4) ^ ((lane >> 1) & 3);

    auto STAGE = [&](int buf, int k0) {
#pragma unroll
        for (int i = 0; i < 4; ++i) {
            const unsigned short* ga =
                Xb + (size_t)(row0 + 16 * i + st_r) * d + k0 + st_g * 8;
            __builtin_amdgcn_global_load_lds((const gbl_uint*)ga,
                                             (lds_uint*)(&As[buf][i * 512]), 16, 0, 0);
            const unsigned short* gb =
                Xb + (size_t)(col0 + 16 * i + st_r) * d + k0 + st_g * 8;
            __builtin_amdgcn_global_load_lds((const gbl_uint*)gb,
                                             (lds_uint*)(&Bs[buf][i * 512]), 16, 0, 0);
        }
    };

    auto COMP = [&](int buf) {
        bf16x8 af[4], bfr[4];
#pragma unroll
        for (int fr = 0; fr < 4; ++fr) {
            int rA = fr * 16 + (lane & 15);
            af[fr] = *reinterpret_cast<const bf16x8*>(&As[buf][rA * 32 + rd_p * 8]);
            bfr[fr] = *reinterpret_cast<const bf16x8*>(&Bs[buf][rA * 32 + rd_p * 8]);
        }
        __builtin_amdgcn_s_setprio(1);
#pragma unroll
        for (int fr = 0; fr < 4; ++fr)
#pragma unroll
            for (int nc = 0; nc < 4; ++nc)
                acc[fr][nc] = __builtin_amdgcn_mfma_f32_16x16x32_bf16(
                    af[fr], bfr[nc], acc[fr][nc], 0, 0, 0);
        __builtin_amdgcn_s_setprio(0);
    };

    const int nt = d / BK;               // 64
    STAGE(0, 0);
    for (int t = 0; t < nt; ++t) {
        const int cur = t & 1;
        if (t + 1 < nt) {
            STAGE(cur ^ 1, (t + 1) * BK);   // 8 loads for t+1 in flight
            WAITV(8);                        // tile t fully landed
        } else {
            WAITV(0);
        }
        COMP(cur);
    }

    // ------------------------------------------------------------------
    // Epilogue. C row = fr*16 + (lane>>4)*4 + j; col = nc*16 + (lane&15).
    // Row stats: in-thread nc + shfl_xor {1,2,4,8}.
    // Col stats (off-diag mirror): in-thread (fr,j) + shfl_xor {16,32}.
    // Tables read directly from global (L1-resident, once per block).
    // ------------------------------------------------------------------
    int tjv[4]; float qjv[4];
#pragma unroll
    for (int nc = 0; nc < 4; ++nc) {
        int gcol = col0 + nc * 16 + (lane & 15);
        tjv[nc] = tgt[gcol];
        qjv[nc] = rowsq[gcol];
    }
    float cs0[4], cs1[4], cs2[4], cs3[4];
#pragma unroll
    for (int nc = 0; nc < 4; ++nc) { cs0[nc] = 0.f; cs1[nc] = 0.f; cs2[nc] = 0.f; cs3[nc] = 0.f; }

#pragma unroll
    for (int fr = 0; fr < 4; ++fr) {
#pragma unroll
        for (int j = 0; j < 4; ++j) {
            int grow = row0 + fr * 16 + (lane >> 4) * 4 + j;
            int ti = tgt[grow];
            float sqi = rowsq[grow];
            float pd = 0.f, pn = 0.f, nd = 0.f, nn = 0.f;
#pragma unroll
            for (int nc = 0; nc < 4; ++nc) {
                int gcol = col0 + nc * 16 + (lane & 15);
                float g = acc[fr][nc][j];
                float d2 = sqi + qjv[nc] - 2.f * g;
                float dist = sqrtf(fmaxf(d2, 1e-12f));
                if (ti == tjv[nc]) {
                    if (grow != gcol) {
                        float e = __expf(dist);
                        pd += e; pn += e * dist;
                        cs0[nc] += e; cs1[nc] += e * dist;
                    }
                } else {
                    float e = __expf(-dist);
                    nd += e; nn += e * dist;
                    cs2[nc] += e; cs3[nc] += e * dist;
                }
            }
            for (int m = 1; m < 16; m <<= 1) {
                pd += __shfl_xor(pd, m);
                pn += __shfl_xor(pn, m);
                nd += __shfl_xor(nd, m);
                nn += __shfl_xor(nn, m);
            }
            if ((lane & 15) == 0) {
                atomicAdd(&stats[grow * 4 + 0], pd);
                atomicAdd(&stats[grow * 4 + 1], pn);
                atomicAdd(&stats[grow * 4 + 2], nd);
                atomicAdd(&stats[grow * 4 + 3], nn);
            }
        }
    }

    if (offdiag) {
#pragma unroll
        for (int nc = 0; nc < 4; ++nc) {
            float a = cs0[nc], b = cs1[nc], c = cs2[nc], e = cs3[nc];
            for (int m = 16; m < 64; m <<= 1) {
                a += __shfl_xor(a, m);
                b += __shfl_xor(b, m);
                c += __shfl_xor(c, m);
                e += __shfl_xor(e, m);
            }
            if (lane < 16) {
                int gcol = col0 + nc * 16 + lane;
                atomicAdd(&stats[gcol * 4 + 0], a);
                atomicAdd(&stats[gcol * 4 + 1], b);
                atomicAdd(&stats[gcol * 4 + 2], c);
                atomicAdd(&stats[gcol * 4 + 3], e);
            }
        }
    }
}

// ---------------------------------------------------------------------------
// Kernel 3: finalize — loss = mean(relu(pos + MARGIN - neg))
// ---------------------------------------------------------------------------
__global__ void finalize_k(const float* __restrict__ stats, float* __restrict__ out, int n) {
    float s = 0.f;
    for (int i = threadIdx.x; i < n; i += blockDim.x) {
        float4 st = *reinterpret_cast<const float4*>(&stats[i * 4]);
        float v = st.y / st.x + N_MARGIN - st.w / st.z;
        s += fmaxf(v, 0.f);
    }
    for (int m = 32; m > 0; m >>= 1) s += __shfl_down(s, m);
    __shared__ float sp[4];
    int lane = threadIdx.x & 63, wv = threadIdx.x >> 6;
    if (lane == 0) sp[wv] = s;
    __syncthreads();
    if (threadIdx.x == 0) out[0] = (sp[0] + sp[1] + sp[2] + sp[3]) / (float)n;
}

extern "C" void kernel_launch(void* const* d_in, const int* in_sizes, int n_in,
                              void* d_out, int out_size, void* d_ws, size_t ws_size,
                              hipStream_t stream) {
    const float* X = (const float*)d_in[0];
    const int* tgt = (const int*)d_in[1];
    const int n = in_sizes[1];             // 4096
    const int d = in_sizes[0] / n;         // 2048

    unsigned short* Xb = (unsigned short*)d_ws;          // n*d bf16 (16 MB)
    float* rowsq = (float*)(Xb + (size_t)n * d);         // n floats
    float* stats = rowsq + n;                            // 4n floats

    hipMemsetAsync(stats, 0, (size_t)n * 4 * sizeof(float), stream);
    norm_cvt_k<<<n / 4, 256, 0, stream>>>(X, Xb, rowsq, d);
    const int nbx = n / BM;                              // 64
    const int nblocks = nbx * (nbx + 1) / 2;             // 2080 upper-tri tiles
    gram_stats_k<<<nblocks, 64, 0, stream>>>(Xb, tgt, rowsq, stats, n, d, nblocks);
    finalize_k<<<1, 256, 0, stream>>>(stats, (float*)d_out, n);
}

// Round 8
// 206.228 us; speedup vs baseline: 1.2345x; 1.1775x over previous
//
#include <hip/hip_runtime.h>
#include <hip/hip_fp8.h>
#include <math.h>

#define N_MARGIN 0.3f
// Gram via fp8-e4m3 MFMA: 128x128 C-tile, BK=64 fp8 (64B rows), double-
// buffered LDS (32KB -> 4+ blocks/CU), 4 waves (2x2), each wave 64x64 =
// 4x4 frags x 2 k-slices of mfma_f32_16x16x32_fp8_fp8.
// Inputs scaled x16 at quantization; epilogue divides acc by 256.
// Upper-tri tiles + mirrored epilogue; supertile serpentine + XCD chunking.
// Global layout is k-interleaved per 64B tile: 16B chunk cg holds
// k=[8cg..8cg+8) and k=[32+8cg..+8) so one ds_read_b128 feeds both k-slices.
// LDS swizzle: phys chunk = kg ^ ((row>>1)&3) (conflict-optimal for b128);
// linear gload_lds dest + inverse-swizzled global source (rule #21).
#define BM 128
#define BKB 64

typedef __attribute__((ext_vector_type(4))) float f32x4;
typedef __attribute__((address_space(3))) unsigned int lds_uint;
typedef __attribute__((address_space(1))) unsigned int gbl_uint;

static __device__ inline unsigned char f2e4m3(float f) {
    __hip_fp8_e4m3 h(f);
    return h.__x;
}
static __device__ inline unsigned pack4(float a, float b, float c, float d) {
    return (unsigned)f2e4m3(a) | ((unsigned)f2e4m3(b) << 8) |
           ((unsigned)f2e4m3(c) << 16) | ((unsigned)f2e4m3(d) << 24);
}

// ---------------------------------------------------------------------------
// Kernel 1: per-row L2-normalize + fp8 convert (x16 scale) with k-interleave.
// One wave per row. Pass 1: coalesced norm. Pass 2: per-lane 2 chunks of 16B,
// chunk c (=t*4+cg) <- k [64t+8cg..+8) and [64t+32+8cg..+8)   (L1 re-read).
// ---------------------------------------------------------------------------
__global__ __launch_bounds__(256)
void norm_cvt_k(const float* __restrict__ X, unsigned char* __restrict__ Xq,
                float* __restrict__ rowsq, int d) {
    const int lane = threadIdx.x & 63;
    const int row = blockIdx.x * 4 + (threadIdx.x >> 6);
    const float* xr = X + (size_t)row * d;

    float ss = 0.f;
#pragma unroll
    for (int c = 0; c < 8; ++c) {
        float4 v = *reinterpret_cast<const float4*>(xr + lane * 4 + c * 256);
        ss += v.x * v.x + v.y * v.y + v.z * v.z + v.w * v.w;
    }
#pragma unroll
    for (int m = 32; m > 0; m >>= 1) ss += __shfl_xor(ss, m);
    float nrm = sqrtf(ss);
    float inv0 = 1.f / (nrm + 1e-12f);
    if (lane == 0) {
        float s = nrm * inv0;
        rowsq[row] = s * s;
    }
    const float inv = 16.f * inv0;   // fold the x16 fp8 scale

    unsigned char* xq = Xq + (size_t)row * d;
#pragma unroll
    for (int h = 0; h < 2; ++h) {
        int c = lane + 64 * h;               // 16B chunk index 0..127
        int k0 = (c >> 2) * 64 + (c & 3) * 8;
        float4 a0 = *reinterpret_cast<const float4*>(xr + k0);
        float4 a1 = *reinterpret_cast<const float4*>(xr + k0 + 4);
        float4 b0 = *reinterpret_cast<const float4*>(xr + k0 + 32);
        float4 b1 = *reinterpret_cast<const float4*>(xr + k0 + 36);
        uint4 o;
        o.x = pack4(a0.x * inv, a0.y * inv, a0.z * inv, a0.w * inv);
        o.y = pack4(a1.x * inv, a1.y * inv, a1.z * inv, a1.w * inv);
        o.z = pack4(b0.x * inv, b0.y * inv, b0.z * inv, b0.w * inv);
        o.w = pack4(b1.x * inv, b1.y * inv, b1.z * inv, b1.w * inv);
        *reinterpret_cast<uint4*>(xq + c * 16) = o;
    }
}

// ---------------------------------------------------------------------------
// Kernel 2: fp8 MFMA Gram (upper-tri) + fused masked-softmax stats.
// ---------------------------------------------------------------------------
__global__ __launch_bounds__(256, 4)
void gram_stats_k(const unsigned char* __restrict__ Xq, const int* __restrict__ tgt,
                  const float* __restrict__ rowsq, float* __restrict__ stats,
                  int n, int d, int nblocks) {
    __shared__ alignas(16) unsigned char As[2][BM * BKB];   // 2 x 8KB
    __shared__ alignas(16) unsigned char Bs[2][BM * BKB];

    const int tid = threadIdx.x;
    const int lane = tid & 63;
    const int w = tid >> 6;          // wave 0..3
    const int wr = w >> 1, wc = w & 1;

    // XCD chunking over supertile serpentine order (528 = 8 * 66)
    const int cpx = nblocks >> 3;
    int rem = (blockIdx.x & 7) * cpx + (blockIdx.x >> 3);

    // serpentine 4x4 supertiles over the 8x8 upper-tri supergrid
    int BY = -1, BX = -1;
    for (int y = 0; y < 8 && BY < 0; ++y) {
        for (int t = 0; t < 8 - y; ++t) {
            int x = (y & 1) ? (7 - t) : (y + t);
            int c = (x == y) ? 10 : 16;
            if (rem < c) { BY = y; BX = x; break; }
            rem -= c;
        }
    }
    int dy, dx;
    if (BX == BY) {
        dy = 0;
        while (rem >= 4 - dy) { rem -= 4 - dy; ++dy; }
        dx = dy + rem;
    } else { dy = rem >> 2; dx = rem & 3; }
    const int by = BY * 4 + dy, bx = BX * 4 + dx;
    const bool offdiag = (by != bx);
    const int row0 = by * BM, col0 = bx * BM;

    f32x4 acc[4][4];
#pragma unroll
    for (int a = 0; a < 4; ++a)
#pragma unroll
        for (int b = 0; b < 4; ++b) acc[a][b] = (f32x4){0.f, 0.f, 0.f, 0.f};

    // staging: instr ia covers rows 16ia..16ia+15 (1KB); lane l -> row
    // 16ia+(l>>2), phys chunk l&3, global chunk (l&3)^((l>>3)&3)
    const int st_r = lane >> 2;
    const int st_g = (lane & 3) ^ ((lane >> 3) & 3);
    // frag read: phys = kg ^ ((row>>1)&3) = (lane>>4) ^ ((lane>>1)&3)
    const int rd_p = (lane >> 4) ^ ((lane >> 1) & 3);

    auto STAGE = [&](int buf, int k0) {
#pragma unroll
        for (int q = 0; q < 2; ++q) {
            int ia = 2 * w + q;   // 0..7
            const unsigned char* ga =
                Xq + (size_t)(row0 + 16 * ia + st_r) * d + k0 + st_g * 16;
            __builtin_amdgcn_global_load_lds((const gbl_uint*)ga,
                                             (lds_uint*)(&As[buf][ia * 1024]), 16, 0, 0);
            const unsigned char* gb =
                Xq + (size_t)(col0 + 16 * ia + st_r) * d + k0 + st_g * 16;
            __builtin_amdgcn_global_load_lds((const gbl_uint*)gb,
                                             (lds_uint*)(&Bs[buf][ia * 1024]), 16, 0, 0);
        }
    };

    auto COMP = [&](int buf) {
        long a0[4], a1[4], b0[4], b1[4];
#pragma unroll
        for (int fr = 0; fr < 4; ++fr) {
            int rA = wr * 64 + fr * 16 + (lane & 15);
            uint4 va = *reinterpret_cast<const uint4*>(&As[buf][rA * 64 + rd_p * 16]);
            a0[fr] = (long)(((unsigned long)va.y << 32) | va.x);
            a1[fr] = (long)(((unsigned long)va.w << 32) | va.z);
            int rB = wc * 64 + fr * 16 + (lane & 15);
            uint4 vb = *reinterpret_cast<const uint4*>(&Bs[buf][rB * 64 + rd_p * 16]);
            b0[fr] = (long)(((unsigned long)vb.y << 32) | vb.x);
            b1[fr] = (long)(((unsigned long)vb.w << 32) | vb.z);
        }
        __builtin_amdgcn_s_setprio(1);
#pragma unroll
        for (int fr = 0; fr < 4; ++fr)
#pragma unroll
            for (int nc = 0; nc < 4; ++nc) {
                acc[fr][nc] = __builtin_amdgcn_mfma_f32_16x16x32_fp8_fp8(
                    a0[fr], b0[nc], acc[fr][nc], 0, 0, 0);
                acc[fr][nc] = __builtin_amdgcn_mfma_f32_16x16x32_fp8_fp8(
                    a1[fr], b1[nc], acc[fr][nc], 0, 0, 0);
            }
        __builtin_amdgcn_s_setprio(0);
    };

    const int nt = d / BKB;              // 32
    STAGE(0, 0);
    __syncthreads();

    for (int t = 0; t < nt; ++t) {
        const int cur = t & 1;
        if (t + 1 < nt) STAGE(cur ^ 1, (t + 1) * BKB);   // prefetch next tile
        COMP(cur);
        __syncthreads();
    }

    // ------------------------------------------------------------------
    // Epilogue. C row = wr*64 + fr*16 + (lane>>4)*4 + j; col = wc*64 +
    // nc*16 + (lane&15). True Gram g = acc/256; d2 = sqi+sqj-2g = s-acc/128.
    // Row stats: in-thread nc + shfl_xor {1,2,4,8}.
    // Col stats (off-diag mirror): in-thread (fr,j) + shfl_xor {16,32}.
    // ------------------------------------------------------------------
    int tjv[4]; float qjv[4];
#pragma unroll
    for (int nc = 0; nc < 4; ++nc) {
        int gcol = col0 + wc * 64 + nc * 16 + (lane & 15);
        tjv[nc] = tgt[gcol];
        qjv[nc] = rowsq[gcol];
    }
    float cs0[4], cs1[4], cs2[4], cs3[4];
#pragma unroll
    for (int nc = 0; nc < 4; ++nc) { cs0[nc] = 0.f; cs1[nc] = 0.f; cs2[nc] = 0.f; cs3[nc] = 0.f; }

#pragma unroll
    for (int fr = 0; fr < 4; ++fr) {
#pragma unroll
        for (int j = 0; j < 4; ++j) {
            int grow = row0 + wr * 64 + fr * 16 + (lane >> 4) * 4 + j;
            int ti = tgt[grow];
            float sqi = rowsq[grow];
            float pd = 0.f, pn = 0.f, nd = 0.f, nn = 0.f;
#pragma unroll
            for (int nc = 0; nc < 4; ++nc) {
                int gcol = col0 + wc * 64 + nc * 16 + (lane & 15);
                float d2 = sqi + qjv[nc] - acc[fr][nc][j] * 0.0078125f;
                float dist = sqrtf(fmaxf(d2, 1e-12f));
                if (ti == tjv[nc]) {
                    if (grow != gcol) {
                        float e = __expf(dist);
                        pd += e; pn += e * dist;
                        cs0[nc] += e; cs1[nc] += e * dist;
                    }
                } else {
                    float e = __expf(-dist);
                    nd += e; nn += e * dist;
                    cs2[nc] += e; cs3[nc] += e * dist;
                }
            }
            for (int m = 1; m < 16; m <<= 1) {
                pd += __shfl_xor(pd, m);
                pn += __shfl_xor(pn, m);
                nd += __shfl_xor(nd, m);
                nn += __shfl_xor(nn, m);
            }
            if ((lane & 15) == 0) {
                atomicAdd(&stats[grow * 4 + 0], pd);
                atomicAdd(&stats[grow * 4 + 1], pn);
                atomicAdd(&stats[grow * 4 + 2], nd);
                atomicAdd(&stats[grow * 4 + 3], nn);
            }
        }
    }

    if (offdiag) {
#pragma unroll
        for (int nc = 0; nc < 4; ++nc) {
            float a = cs0[nc], b = cs1[nc], c = cs2[nc], e = cs3[nc];
            for (int m = 16; m < 64; m <<= 1) {
                a += __shfl_xor(a, m);
                b += __shfl_xor(b, m);
                c += __shfl_xor(c, m);
                e += __shfl_xor(e, m);
            }
            if (lane < 16) {
                int gcol = col0 + wc * 64 + nc * 16 + lane;
                atomicAdd(&stats[gcol * 4 + 0], a);
                atomicAdd(&stats[gcol * 4 + 1], b);
                atomicAdd(&stats[gcol * 4 + 2], c);
                atomicAdd(&stats[gcol * 4 + 3], e);
            }
        }
    }
}

// ---------------------------------------------------------------------------
// Kernel 3: finalize — loss = mean(relu(pos + MARGIN - neg))
// ---------------------------------------------------------------------------
__global__ void finalize_k(const float* __restrict__ stats, float* __restrict__ out, int n) {
    float s = 0.f;
    for (int i = threadIdx.x; i < n; i += blockDim.x) {
        float4 st = *reinterpret_cast<const float4*>(&stats[i * 4]);
        float v = st.y / st.x + N_MARGIN - st.w / st.z;
        s += fmaxf(v, 0.f);
    }
    for (int m = 32; m > 0; m >>= 1) s += __shfl_down(s, m);
    __shared__ float sp[4];
    int lane = threadIdx.x & 63, wv = threadIdx.x >> 6;
    if (lane == 0) sp[wv] = s;
    __syncthreads();
    if (threadIdx.x == 0) out[0] = (sp[0] + sp[1] + sp[2] + sp[3]) / (float)n;
}

extern "C" void kernel_launch(void* const* d_in, const int* in_sizes, int n_in,
                              void* d_out, int out_size, void* d_ws, size_t ws_size,
                              hipStream_t stream) {
    const float* X = (const float*)d_in[0];
    const int* tgt = (const int*)d_in[1];
    const int n = in_sizes[1];             // 4096
    const int d = in_sizes[0] / n;         // 2048

    unsigned char* Xq = (unsigned char*)d_ws;            // n*d fp8 (8 MB)
    float* rowsq = (float*)(Xq + (size_t)n * d);         // n floats
    float* stats = rowsq + n;                            // 4n floats

    hipMemsetAsync(stats, 0, (size_t)n * 4 * sizeof(float), stream);
    norm_cvt_k<<<n / 4, 256, 0, stream>>>(X, Xq, rowsq, d);
    const int nbx = n / BM;                              // 32
    const int nblocks = nbx * (nbx + 1) / 2;             // 528 upper-tri tiles
    gram_stats_k<<<nblocks, 256, 0, stream>>>(Xq, tgt, rowsq, stats, n, d, nblocks);
    finalize_k<<<1, 256, 0, stream>>>(stats, (float*)d_out, n);
}